// Round 8
// baseline (1554.960 us; speedup 1.0000x reference)
//
#include <hip/hip_runtime.h>
#include <stdint.h>

typedef __attribute__((ext_vector_type(8))) __bf16 bf16x8;
typedef __attribute__((ext_vector_type(4))) float f32x4;
typedef __attribute__((ext_vector_type(4))) unsigned int uint4v;

#define DI __device__ __forceinline__
#define MFMA_(a,b,c) __builtin_amdgcn_mfma_f32_16x16x32_bf16(a,b,c,0,0,0)

static constexpr int B_ = 2048;
static constexpr int T_ = 100;

DI float bf2f(unsigned short u){
  unsigned int i = ((unsigned int)u) << 16;
  float f; __builtin_memcpy(&f, &i, 4); return f;
}
DI unsigned short f2bf(float f){
  unsigned int x; __builtin_memcpy(&x, &f, 4);
  unsigned int r = (x + 0x7fffu + ((x >> 16) & 1u)) >> 16;
  return (unsigned short)r;
}
// HW packed rounding: D[15:0]=bf16(a), D[31:16]=bf16(b). RNE, matches f2bf.
DI unsigned int pk2bf(float a, float b){
  unsigned int r;
  asm("v_cvt_pk_bf16_f32 %0, %1, %2" : "=v"(r) : "v"(a), "v"(b));
  return r;
}
DI float rcp_(float x){ return __builtin_amdgcn_rcpf(x); }
DI float sig_(float x){ return rcp_(1.0f + __expf(-x)); }
DI float tanh_(float x){ return 1.0f - 2.0f * rcp_(__expf(2.0f * x) + 1.0f); }

// 2-pass split-weight MFMA dot: A(bf16) x (Bhi + Blo). Two independent chains.
template<int KS>
DI f32x4 dot2(const bf16x8* aH, const bf16x8* bH, const bf16x8* bL, f32x4 ini)
{
  f32x4 p = ini;
  f32x4 q = (f32x4){0.f,0.f,0.f,0.f};
  #pragma unroll
  for (int s = 0; s < KS; ++s){
    p = MFMA_(aH[s], bH[s], p);
    q = MFMA_(aH[s], bL[s], q);
  }
  return p + q;
}

// LSTM pointwise: gates i,f,g,o -> c,h; h rounded to bf16 via cvt_pk.
DI void pw(const f32x4 (&acc)[4], float (&cc)[4], float (&hv)[4],
           unsigned short (&hH)[4])
{
  #pragma unroll
  for (int r = 0; r < 4; ++r){
    float iv = sig_(acc[0][r]);
    float fv = sig_(acc[1][r]);
    float gv = tanh_(acc[2][r]);
    float ov = sig_(acc[3][r]);
    cc[r] = fv * cc[r] + iv * gv;
    hv[r] = ov * tanh_(cc[r]);
  }
  unsigned int u01 = pk2bf(hv[0], hv[1]);
  unsigned int u23 = pk2bf(hv[2], hv[3]);
  hH[0] = (unsigned short)u01; hH[1] = (unsigned short)(u01 >> 16);
  hH[2] = (unsigned short)u23; hH[3] = (unsigned short)(u23 >> 16);
}

// ---------------------------------------------------------------------------
// Pack all weights (fp32 in) into split hi/lo bf16 MFMA B-fragments.
// slot 2*fid+0 = hi, 2*fid+1 = lo. fid layout:
// L1(4096) L2(1536) L3(2048) L4(4096) PROJ(512) = 12288 frags.
// B-frag: lane l holds B[k = 32*s + 8*(l>>4) + e][col = 16*n + (l&15)], e=0..7.
// ---------------------------------------------------------------------------
__global__ __launch_bounds__(256) void prep_frags(
    const float* __restrict__ e1_wih, const float* __restrict__ e1_whh,
    const float* __restrict__ e2_wih, const float* __restrict__ e2_whh,
    const float* __restrict__ d1_whh,
    const float* __restrict__ d2_wih, const float* __restrict__ d2_whh,
    const float* __restrict__ w_out,
    unsigned short* __restrict__ dst)
{
  int ofid = blockIdx.x * 256 + threadIdx.x;
  if (ofid >= 24576) return;
  int piece = ofid & 1, fid = ofid >> 1;
  int layer, local, KS;
  if (fid < 4096)      { layer = 0; local = fid;         KS = 4; }
  else if (fid < 5632) { layer = 1; local = fid - 4096;  KS = 3; }
  else if (fid < 7680) { layer = 2; local = fid - 5632;  KS = 2; }
  else if (fid < 11776){ layer = 3; local = fid - 7680;  KS = 4; }
  else                 { layer = 4; local = fid - 11776; KS = 2; }
  int lane = local & 63;
  int ns = local >> 6;
  int s = ns % KS, n = ns / KS;
  int col = 16 * n + (lane & 15);
  int kb = 32 * s + 8 * (lane >> 4);
  union { unsigned short u[8]; uint4v v; } pk;
  #pragma unroll
  for (int e = 0; e < 8; ++e){
    int k = kb + e;
    float w = 0.0f;
    if (layer == 0){                       // e1: x(51 pad64)|h1(64); K=128, C=256
      if (k < 51) w = e1_wih[col * 51 + k];
      else if (k >= 64) w = e1_whh[col * 64 + (k - 64)];
    } else if (layer == 1){                // e2: h1(64)|h2(24 pad32); K=96, C=128
      int q = col >> 5, jj = col & 31;
      if (jj < 24){
        int r = q * 24 + jj;
        if (k < 64) w = e2_wih[r * 64 + k];
        else if (k < 88) w = e2_whh[r * 24 + (k - 64)];
      }
    } else if (layer == 2){                // d1 recurrent only; K=64, C=256
      w = d1_whh[col * 64 + k];
    } else if (layer == 3){                // d2: h3(64)|h4(64); K=128, C=256
      if (k < 64) w = d2_wih[col * 64 + k];
      else w = d2_whh[col * 64 + (k - 64)];
    } else {                               // proj: K=64, C=64 (51 used)
      if (col < 51) w = w_out[col * 64 + k];
    }
    unsigned short hi = f2bf(w);
    pk.u[e] = piece ? f2bf(w - bf2f(hi)) : hi;
  }
  *(uint4v*)(dst + (size_t)ofid * 8) = pk.v;
}

// Decoder-1 constant input contribution (exact fp32):
// gx[s][col] = b_ih[col] + b_hh[col] + z[s,:]·W_ih[col,:]
__global__ __launch_bounds__(256) void gx_k(
    const float* __restrict__ z, const float* __restrict__ d1_wih,
    const float* __restrict__ bih, const float* __restrict__ bhh,
    float* __restrict__ gx)
{
  int s = blockIdx.x, col = threadIdx.x;
  float acc = bih[col] + bhh[col];
  #pragma unroll
  for (int k = 0; k < 24; ++k)
    acc += z[s * 24 + k] * d1_wih[col * 24 + k];
  gx[s * 256 + col] = acc;
}

// ---------------------------------------------------------------------------
// F1: fused encoder (e1 + e2), 32 batch rows/block, 8 waves (2/SIMD).
// Waves 0-3: row-group 0; waves 4-7: row-group 1 (SIMD pairs (w, w+4) run
// identical roles on different rows -> latency hiding). Within a group:
// all 4 waves compute e1; waves 0,1 run e2 (lag 1); waves 2,3 stage x.
// NOTE: launch_bounds min-waves MUST be 1 — declaring 2 caps VGPR at 128 and
// spills the weight fragments to scratch (round-7 regression: 292->1554 us).
// ---------------------------------------------------------------------------
__global__ __launch_bounds__(512, 1) void fused_enc(
    const float* xseq,
    const unsigned short* __restrict__ bf1u,
    const unsigned short* __restrict__ bf2u,
    const float* __restrict__ e1_bih, const float* __restrict__ e1_bhh,
    const float* __restrict__ e2_bih, const float* __restrict__ e2_bhh,
    float* __restrict__ zout)
{
  constexpr int SA1 = 136;                 // A1 row stride (ushorts): x(64)|h1(64) pad
  constexpr int SA2 = 104;                 // A2 row stride: h1(64)|h2(32) pad
  __shared__ __align__(16) unsigned short A1H[2][32 * SA1];
  __shared__ __align__(16) unsigned short A2H[2][32 * SA2];

  const int tid = threadIdx.x;
  const int wid8 = tid >> 6;               // 0..7
  const int grp = wid8 >> 2;               // row group 0/1
  const int wid = wid8 & 3;                // role wave within group
  const int gtid = tid & 255;              // thread id within group
  const int lane = tid & 63;
  const int l15 = lane & 15, l4 = lane >> 4;
  const int jj = 16 * wid + l15;
  const int rb = grp * 16;                 // LDS row base of this group
  const int s0 = blockIdx.x * 32 + rb;     // global batch base of this group
  const bool isE2 = (wid < 2);
  const bool isXW = (wid >= 2);
  const int xt = gtid - 128;               // 0..127 on staging waves

  const bf16x8* f1 = (const bf16x8*)bf1u;
  const bf16x8* f2 = (const bf16x8*)bf2u;
  bf16x8 b1H[16], b1L[16];                 // e1 frags [g*4+s]
  #pragma unroll
  for (int g = 0; g < 4; ++g)
    #pragma unroll
    for (int s = 0; s < 4; ++s){
      size_t idx = (size_t)(((wid + 4 * g) * 4 + s) * 64 + lane);
      b1H[g * 4 + s] = f1[2 * idx];
      b1L[g * 4 + s] = f1[2 * idx + 1];
    }
  bf16x8 b2H[12], b2L[12];                 // e2 frags [g*3+s] (e2 waves)
  if (isE2){
    #pragma unroll
    for (int g = 0; g < 4; ++g)
      #pragma unroll
      for (int s = 0; s < 3; ++s){
        size_t idx = (size_t)(((wid + 2 * g) * 3 + s) * 64 + lane);
        b2H[g * 3 + s] = f2[2 * idx];
        b2L[g * 3 + s] = f2[2 * idx + 1];
      }
  }

  f32x4 init1[4], init2[4];
  #pragma unroll
  for (int g = 0; g < 4; ++g){
    float b = e1_bih[g * 64 + jj] + e1_bhh[g * 64 + jj];
    init1[g] = (f32x4){b, b, b, b};
    float b2 = 0.0f;
    if (isE2 && jj < 24) b2 = e2_bih[g * 24 + jj] + e2_bhh[g * 24 + jj];
    init2[g] = (f32x4){b2, b2, b2, b2};
  }

  for (int i = tid; i < 32 * SA1; i += 512){ A1H[0][i] = 0; A1H[1][i] = 0; }
  for (int i = tid; i < 32 * SA2; i += 512){ A2H[0][i] = 0; A2H[1][i] = 0; }
  __syncthreads();
  {
    const size_t s0b = (size_t)blockIdx.x * 32;
    #pragma unroll
    for (int it = 0; it < 4; ++it){         // stage x_0 (all 512 threads, 32 rows)
      int idx = tid + it * 512, row = idx >> 6, k = idx & 63;
      float v = (k < 51) ? xseq[((s0b + row) * T_ + 0) * 51 + k] : 0.0f;
      A1H[0][row * SA1 + k] = f2bf(v);
    }
  }
  __syncthreads();

  float xsA[8], xsB[8];
  if (isXW){
    #pragma unroll
    for (int it = 0; it < 8; ++it){         // prefetch x_1, x_2 (staging waves)
      int idx = xt + it * 128, row = idx >> 6, k = idx & 63;
      xsA[it] = (k < 51) ? xseq[((size_t)(s0 + row) * T_ + 1) * 51 + k] : 0.0f;
      xsB[it] = (k < 51) ? xseq[((size_t)(s0 + row) * T_ + 2) * 51 + k] : 0.0f;
    }
  }
  float cc1[4] = {0.f,0.f,0.f,0.f}, cc2[4] = {0.f,0.f,0.f,0.f};

#define ENC_STEP(TCUR, BSEL, XW)                                               \
  {                                                                            \
    const int t = (TCUR);                                                      \
    bf16x8 a1H[4], a2H[3];                                                     \
    if (t < T_){                                                               \
      _Pragma("unroll")                                                        \
      for (int s = 0; s < 4; ++s)                                              \
        a1H[s] = *(const bf16x8*)&A1H[BSEL][(rb + l15) * SA1 + 32 * s + 8 * l4]; \
    }                                                                          \
    if (isE2 && t >= 1 && t <= T_){                                            \
      _Pragma("unroll")                                                        \
      for (int s = 0; s < 3; ++s)                                              \
        a2H[s] = *(const bf16x8*)&A2H[BSEL][(rb + l15) * SA2 + 32 * s + 8 * l4]; \
    }                                                                          \
    if (t < T_){  /* e1 step t: all waves */                                   \
      f32x4 acc[4];                                                            \
      _Pragma("unroll")                                                        \
      for (int g = 0; g < 4; ++g)                                              \
        acc[g] = dot2<4>(a1H, &b1H[g * 4], &b1L[g * 4], init1[g]);             \
      float hv[4]; unsigned short hH[4];                                       \
      pw(acc, cc1, hv, hH);                                                    \
      _Pragma("unroll")                                                        \
      for (int r = 0; r < 4; ++r){                                             \
        int rw = rb + 4 * l4 + r;                                              \
        A1H[BSEL ^ 1][rw * SA1 + 64 + jj] = hH[r];                             \
        A2H[BSEL ^ 1][rw * SA2 + jj] = hH[r];                                  \
      }                                                                        \
      if (isXW && t + 1 < T_){  /* x_{t+1} -> LDS, prefetch x_{t+3} */         \
        _Pragma("unroll")                                                      \
        for (int it = 0; it < 8; it += 2){                                     \
          int idx = xt + it * 128;                                             \
          int row0_ = idx >> 6, k0_ = idx & 63;                                \
          int row1_ = (idx + 128) >> 6, k1_ = (idx + 128) & 63;                \
          unsigned int u = pk2bf(XW[it], XW[it + 1]);                          \
          A1H[BSEL ^ 1][(rb + row0_) * SA1 + k0_] = (unsigned short)u;         \
          A1H[BSEL ^ 1][(rb + row1_) * SA1 + k1_] = (unsigned short)(u >> 16); \
        }                                                                      \
        if (t + 3 < T_){                                                       \
          _Pragma("unroll")                                                    \
          for (int it = 0; it < 8; ++it){                                      \
            int idx = xt + it * 128, row = idx >> 6, k = idx & 63;             \
            XW[it] = (k < 51) ? xseq[((size_t)(s0 + row) * T_ + (t + 3)) * 51 + k] : 0.0f; \
          }                                                                    \
        }                                                                      \
      }                                                                        \
    }                                                                          \
    if (isE2 && t >= 1 && t <= T_){  /* e2 computes h2_{t-1} */                \
      f32x4 acc[4];                                                            \
      _Pragma("unroll")                                                        \
      for (int g = 0; g < 4; ++g)                                              \
        acc[g] = dot2<3>(a2H, &b2H[g * 3], &b2L[g * 3], init2[g]);             \
      float hv[4]; unsigned short hH[4];                                       \
      pw(acc, cc2, hv, hH);                                                    \
      if (jj < 24){                                                            \
        _Pragma("unroll")                                                      \
        for (int r = 0; r < 4; ++r)                                            \
          A2H[BSEL ^ 1][(rb + 4 * l4 + r) * SA2 + 64 + jj] = hH[r];            \
        if (t == T_){                                                          \
          _Pragma("unroll")                                                    \
          for (int r = 0; r < 4; ++r)                                          \
            zout[(size_t)(s0 + 4 * l4 + r) * 24 + jj] = hv[r];                 \
        }                                                                      \
      }                                                                        \
    }                                                                          \
    asm volatile("s_waitcnt lgkmcnt(0)\n\ts_barrier" ::: "memory");            \
  }

  #pragma unroll 1
  for (int tt = 0; tt < 102; tt += 2){
    ENC_STEP(tt,     0, xsA)
    ENC_STEP(tt + 1, 1, xsB)
  }
#undef ENC_STEP
}

// ---------------------------------------------------------------------------
// F2: fused decoder (d1 + d2 + proj), 32 rows/block, 8 waves (2/SIMD),
// waves 0-3 row-group 0, waves 4-7 row-group 1, all roles on every wave.
// Step t: d1 h3_t (t<=99); d2 h4_{t-1} (1<=t<=100); proj of h4_{t-2} (t>=2).
// ---------------------------------------------------------------------------
__global__ __launch_bounds__(512, 1) void fused_dec(
    const float* __restrict__ gxin,
    const unsigned short* __restrict__ bf3u,
    const unsigned short* __restrict__ bf4u,
    const unsigned short* __restrict__ bfpu,
    const float* __restrict__ d2_bih, const float* __restrict__ d2_bhh,
    const float* __restrict__ b_out,
    float* out)
{
  constexpr int SA3 = 72;                  // A3: h3(64) pad
  constexpr int SA4 = 136;                 // A4: h3(64)|h4(64) pad
  __shared__ __align__(16) unsigned short A3H[2][32 * SA3];
  __shared__ __align__(16) unsigned short A4H[2][32 * SA4];

  const int tid = threadIdx.x;
  const int wid8 = tid >> 6;
  const int grp = wid8 >> 2;
  const int wid = wid8 & 3;
  const int lane = tid & 63;
  const int l15 = lane & 15, l4 = lane >> 4;
  const int jj = 16 * wid + l15;
  const int rb = grp * 16;
  const int s0 = blockIdx.x * 32 + rb;

  const bf16x8* f3 = (const bf16x8*)bf3u;
  const bf16x8* f4 = (const bf16x8*)bf4u;
  const bf16x8* fp = (const bf16x8*)bfpu;
  bf16x8 b3H[8], b3L[8];                   // d1 [g*2+s]
  bf16x8 b4H[16], b4L[16];                 // d2 [g*4+s]
  bf16x8 bpH[2], bpL[2];                   // proj [s]
  #pragma unroll
  for (int g = 0; g < 4; ++g){
    #pragma unroll
    for (int s = 0; s < 2; ++s){
      size_t idx = (size_t)(((wid + 4 * g) * 2 + s) * 64 + lane);
      b3H[g * 2 + s] = f3[2 * idx];
      b3L[g * 2 + s] = f3[2 * idx + 1];
    }
    #pragma unroll
    for (int s = 0; s < 4; ++s){
      size_t idx = (size_t)(((wid + 4 * g) * 4 + s) * 64 + lane);
      b4H[g * 4 + s] = f4[2 * idx];
      b4L[g * 4 + s] = f4[2 * idx + 1];
    }
  }
  #pragma unroll
  for (int s = 0; s < 2; ++s){
    size_t idx = (size_t)((wid * 2 + s) * 64 + lane);
    bpH[s] = fp[2 * idx];
    bpL[s] = fp[2 * idx + 1];
  }

  f32x4 init3[4], init4[4];
  #pragma unroll
  for (int g = 0; g < 4; ++g){
    #pragma unroll
    for (int r = 0; r < 4; ++r)
      init3[g][r] = gxin[(size_t)(s0 + 4 * l4 + r) * 256 + jj + 64 * g];
    float b = d2_bih[g * 64 + jj] + d2_bhh[g * 64 + jj];
    init4[g] = (f32x4){b, b, b, b};
  }
  float bp = (jj < 51) ? b_out[jj] : 0.0f;
  const f32x4 biasP = (f32x4){bp, bp, bp, bp};

  for (int i = tid; i < 32 * SA3; i += 512){ A3H[0][i] = 0; A3H[1][i] = 0; }
  for (int i = tid; i < 32 * SA4; i += 512){ A4H[0][i] = 0; A4H[1][i] = 0; }
  __syncthreads();

  float cc3[4] = {0.f,0.f,0.f,0.f}, cc4[4] = {0.f,0.f,0.f,0.f};

#define DEC_STEP(TCUR, BSEL)                                                   \
  {                                                                            \
    const int t = (TCUR);                                                      \
    bf16x8 a3H[2], a4H[4];                                                     \
    if (t < T_){                                                               \
      _Pragma("unroll")                                                        \
      for (int s = 0; s < 2; ++s)                                              \
        a3H[s] = *(const bf16x8*)&A3H[BSEL][(rb + l15) * SA3 + 32 * s + 8 * l4]; \
    }                                                                          \
    if (t >= 1){                                                               \
      _Pragma("unroll")                                                        \
      for (int s = 0; s < 4; ++s)                                              \
        a4H[s] = *(const bf16x8*)&A4H[BSEL][(rb + l15) * SA4 + 32 * s + 8 * l4]; \
    }                                                                          \
    if (t < T_){  /* d1 step t */                                              \
      f32x4 acc[4];                                                            \
      _Pragma("unroll")                                                        \
      for (int g = 0; g < 4; ++g)                                              \
        acc[g] = dot2<2>(a3H, &b3H[g * 2], &b3L[g * 2], init3[g]);             \
      float hv[4]; unsigned short hH[4];                                       \
      pw(acc, cc3, hv, hH);                                                    \
      _Pragma("unroll")                                                        \
      for (int r = 0; r < 4; ++r){                                             \
        int rw = rb + 4 * l4 + r;                                              \
        A3H[BSEL ^ 1][rw * SA3 + jj] = hH[r];                                  \
        A4H[BSEL ^ 1][rw * SA4 + jj] = hH[r];                                  \
      }                                                                        \
    }                                                                          \
    if (t >= 1 && t <= T_){  /* d2 computes h4_{t-1} */                        \
      f32x4 acc[4];                                                            \
      _Pragma("unroll")                                                        \
      for (int g = 0; g < 4; ++g)                                              \
        acc[g] = dot2<4>(a4H, &b4H[g * 4], &b4L[g * 4], init4[g]);             \
      float hv[4]; unsigned short hH[4];                                       \
      pw(acc, cc4, hv, hH);                                                    \
      _Pragma("unroll")                                                        \
      for (int r = 0; r < 4; ++r)                                              \
        A4H[BSEL ^ 1][(rb + 4 * l4 + r) * SA4 + 64 + jj] = hH[r];              \
    }                                                                          \
    if (t >= 2){  /* proj of h4_{t-2} (A4 h-section = a4H[2..3]) */            \
      f32x4 pr = dot2<2>(&a4H[2], bpH, bpL, biasP);                            \
      if (jj < 51){                                                            \
        _Pragma("unroll")                                                      \
        for (int r = 0; r < 4; ++r)                                            \
          out[((size_t)(s0 + 4 * l4 + r) * T_ + (t - 2)) * 51 + jj] = pr[r];   \
      }                                                                        \
    }                                                                          \
    asm volatile("s_waitcnt lgkmcnt(0)\n\ts_barrier" ::: "memory");            \
  }

  #pragma unroll 1
  for (int tt = 0; tt < 102; tt += 2){
    DEC_STEP(tt,     0)
    DEC_STEP(tt + 1, 1)
  }
#undef DEC_STEP
}

extern "C" void kernel_launch(void* const* d_in, const int* in_sizes, int n_in,
                              void* d_out, int out_size, void* d_ws, size_t ws_size,
                              hipStream_t stream)
{
  (void)in_sizes; (void)n_in; (void)out_size; (void)ws_size;
  const float* x      = (const float*)d_in[0];
  const float* e1_wih = (const float*)d_in[1];
  const float* e1_whh = (const float*)d_in[2];
  const float* e1_bih = (const float*)d_in[3];
  const float* e1_bhh = (const float*)d_in[4];
  const float* e2_wih = (const float*)d_in[5];
  const float* e2_whh = (const float*)d_in[6];
  const float* e2_bih = (const float*)d_in[7];
  const float* e2_bhh = (const float*)d_in[8];
  const float* d1_wih = (const float*)d_in[9];
  const float* d1_whh = (const float*)d_in[10];
  const float* d1_bih = (const float*)d_in[11];
  const float* d1_bhh = (const float*)d_in[12];
  const float* d2_wih = (const float*)d_in[13];
  const float* d2_whh = (const float*)d_in[14];
  const float* d2_bih = (const float*)d_in[15];
  const float* d2_bhh = (const float*)d_in[16];
  const float* w_out  = (const float*)d_in[17];
  const float* b_out  = (const float*)d_in[18];

  char* ws = (char*)d_ws;
  unsigned short* bfrag = (unsigned short*)ws;                   // 393,216 B
  const size_t BF_L2 = 131072, BF_L3 = 180224, BF_L4 = 245760, BF_PR = 376832;
  float* zbuf  = (float*)(ws + 393216);                          // 196,608 B
  float* gxbuf = (float*)(ws + 393216 + 196608);                 // 2,097,152 B

  prep_frags<<<96, 256, 0, stream>>>(e1_wih, e1_whh, e2_wih, e2_whh,
                                     d1_whh, d2_wih, d2_whh, w_out, bfrag);
  // F1: x -> (e1 -> e2, fused) -> z[B,24]
  fused_enc<<<64, 512, 0, stream>>>(
      x, bfrag, bfrag + BF_L2 / 2, e1_bih, e1_bhh, e2_bih, e2_bhh, zbuf);
  // decoder-1 constant input contribution (exact fp32)
  gx_k<<<2048, 256, 0, stream>>>(zbuf, d1_wih, d1_bih, d1_bhh, gxbuf);
  // F2: gx -> (d1 -> d2 -> proj, fused) -> recon[B,T,51] fp32
  fused_dec<<<64, 512, 0, stream>>>(
      gxbuf, bfrag + BF_L3 / 2, bfrag + BF_L4 / 2, bfrag + BF_PR / 2,
      d2_bih, d2_bhh, b_out, (float*)d_out);
}

// Round 9
// 536.429 us; speedup vs baseline: 2.8987x; 2.8987x over previous
//
#include <hip/hip_runtime.h>
#include <stdint.h>

typedef __attribute__((ext_vector_type(8))) __bf16 bf16x8;
typedef __attribute__((ext_vector_type(4))) float f32x4;
typedef __attribute__((ext_vector_type(4))) unsigned int uint4v;

#define DI __device__ __forceinline__
#define MFMA_(a,b,c) __builtin_amdgcn_mfma_f32_16x16x32_bf16(a,b,c,0,0,0)

static constexpr int B_ = 2048;
static constexpr int T_ = 100;

DI float bf2f(unsigned short u){
  unsigned int i = ((unsigned int)u) << 16;
  float f; __builtin_memcpy(&f, &i, 4); return f;
}
DI unsigned short f2bf(float f){
  unsigned int x; __builtin_memcpy(&x, &f, 4);
  unsigned int r = (x + 0x7fffu + ((x >> 16) & 1u)) >> 16;
  return (unsigned short)r;
}
// HW packed rounding: D[15:0]=bf16(a), D[31:16]=bf16(b). RNE, matches f2bf.
DI unsigned int pk2bf(float a, float b){
  unsigned int r;
  asm("v_cvt_pk_bf16_f32 %0, %1, %2" : "=v"(r) : "v"(a), "v"(b));
  return r;
}
DI float rcp_(float x){ return __builtin_amdgcn_rcpf(x); }
DI float sig_(float x){ return rcp_(1.0f + __expf(-x)); }
DI float tanh_(float x){ return 1.0f - 2.0f * rcp_(__expf(2.0f * x) + 1.0f); }

// 2-pass split-weight MFMA dot: A(bf16) x (Bhi + Blo). Two independent chains.
template<int KS>
DI f32x4 dot2(const bf16x8* aH, const bf16x8* bH, const bf16x8* bL, f32x4 ini)
{
  f32x4 p = ini;
  f32x4 q = (f32x4){0.f,0.f,0.f,0.f};
  #pragma unroll
  for (int s = 0; s < KS; ++s){
    p = MFMA_(aH[s], bH[s], p);
    q = MFMA_(aH[s], bL[s], q);
  }
  return p + q;
}

// LSTM pointwise: gates i,f,g,o -> c,h; h rounded to bf16 via cvt_pk.
DI void pw(const f32x4 (&acc)[4], float (&cc)[4], float (&hv)[4],
           unsigned short (&hH)[4])
{
  #pragma unroll
  for (int r = 0; r < 4; ++r){
    float iv = sig_(acc[0][r]);
    float fv = sig_(acc[1][r]);
    float gv = tanh_(acc[2][r]);
    float ov = sig_(acc[3][r]);
    cc[r] = fv * cc[r] + iv * gv;
    hv[r] = ov * tanh_(cc[r]);
  }
  unsigned int u01 = pk2bf(hv[0], hv[1]);
  unsigned int u23 = pk2bf(hv[2], hv[3]);
  hH[0] = (unsigned short)u01; hH[1] = (unsigned short)(u01 >> 16);
  hH[2] = (unsigned short)u23; hH[3] = (unsigned short)(u23 >> 16);
}

// ---------------------------------------------------------------------------
// Pack all weights (fp32 in) into split hi/lo bf16 MFMA B-fragments.
// slot 2*fid+0 = hi, 2*fid+1 = lo. fid layout:
// L1(4096) L2(1536) L3(2048) L4(4096) PROJ(512) = 12288 frags.
// B-frag: lane l holds B[k = 32*s + 8*(l>>4) + e][col = 16*n + (l&15)], e=0..7.
// ---------------------------------------------------------------------------
__global__ __launch_bounds__(256) void prep_frags(
    const float* __restrict__ e1_wih, const float* __restrict__ e1_whh,
    const float* __restrict__ e2_wih, const float* __restrict__ e2_whh,
    const float* __restrict__ d1_whh,
    const float* __restrict__ d2_wih, const float* __restrict__ d2_whh,
    const float* __restrict__ w_out,
    unsigned short* __restrict__ dst)
{
  int ofid = blockIdx.x * 256 + threadIdx.x;
  if (ofid >= 24576) return;
  int piece = ofid & 1, fid = ofid >> 1;
  int layer, local, KS;
  if (fid < 4096)      { layer = 0; local = fid;         KS = 4; }
  else if (fid < 5632) { layer = 1; local = fid - 4096;  KS = 3; }
  else if (fid < 7680) { layer = 2; local = fid - 5632;  KS = 2; }
  else if (fid < 11776){ layer = 3; local = fid - 7680;  KS = 4; }
  else                 { layer = 4; local = fid - 11776; KS = 2; }
  int lane = local & 63;
  int ns = local >> 6;
  int s = ns % KS, n = ns / KS;
  int col = 16 * n + (lane & 15);
  int kb = 32 * s + 8 * (lane >> 4);
  union { unsigned short u[8]; uint4v v; } pk;
  #pragma unroll
  for (int e = 0; e < 8; ++e){
    int k = kb + e;
    float w = 0.0f;
    if (layer == 0){                       // e1: x(51 pad64)|h1(64); K=128, C=256
      if (k < 51) w = e1_wih[col * 51 + k];
      else if (k >= 64) w = e1_whh[col * 64 + (k - 64)];
    } else if (layer == 1){                // e2: h1(64)|h2(24 pad32); K=96, C=128
      int q = col >> 5, jj = col & 31;
      if (jj < 24){
        int r = q * 24 + jj;
        if (k < 64) w = e2_wih[r * 64 + k];
        else if (k < 88) w = e2_whh[r * 24 + (k - 64)];
      }
    } else if (layer == 2){                // d1 recurrent only; K=64, C=256
      w = d1_whh[col * 64 + k];
    } else if (layer == 3){                // d2: h3(64)|h4(64); K=128, C=256
      if (k < 64) w = d2_wih[col * 64 + k];
      else w = d2_whh[col * 64 + (k - 64)];
    } else {                               // proj: K=64, C=64 (51 used)
      if (col < 51) w = w_out[col * 64 + k];
    }
    unsigned short hi = f2bf(w);
    pk.u[e] = piece ? f2bf(w - bf2f(hi)) : hi;
  }
  *(uint4v*)(dst + (size_t)ofid * 8) = pk.v;
}

// Decoder-1 constant input contribution (exact fp32):
// gx[s][col] = b_ih[col] + b_hh[col] + z[s,:]·W_ih[col,:]
__global__ __launch_bounds__(256) void gx_k(
    const float* __restrict__ z, const float* __restrict__ d1_wih,
    const float* __restrict__ bih, const float* __restrict__ bhh,
    float* __restrict__ gx)
{
  int s = blockIdx.x, col = threadIdx.x;
  float acc = bih[col] + bhh[col];
  #pragma unroll
  for (int k = 0; k < 24; ++k)
    acc += z[s * 24 + k] * d1_wih[col * 24 + k];
  gx[s * 256 + col] = acc;
}

// ---------------------------------------------------------------------------
// F1: fused encoder (e1 + e2), ILP-2: 32 batch rows/block, 256 threads
// (4 waves, 1 wave/SIMD, full 512-reg unified budget — NO 512-thread blocks:
// 8-wave blocks force 2 waves/SIMD -> 128-VGPR cap -> weight spill, r7/r8).
// Each wave computes its 16-col e1 gate tile for BOTH row groups (0-15,
// 16-31) — two independent streams fill each other's latency. e2 is split:
// waves 0,1 -> group 0; waves 2,3 -> group 1. x staging across all threads.
// ---------------------------------------------------------------------------
__global__ __launch_bounds__(256, 1) void fused_enc(
    const float* xseq,
    const unsigned short* __restrict__ bf1u,
    const unsigned short* __restrict__ bf2u,
    const float* __restrict__ e1_bih, const float* __restrict__ e1_bhh,
    const float* __restrict__ e2_bih, const float* __restrict__ e2_bhh,
    float* __restrict__ zout)
{
  constexpr int SA1 = 136;                 // A1 row stride (ushorts): x(64)|h1(64) pad
  constexpr int SA2 = 104;                 // A2 row stride: h1(64)|h2(32) pad
  __shared__ __align__(16) unsigned short A1H[2][32 * SA1];
  __shared__ __align__(16) unsigned short A2H[2][32 * SA2];

  const int tid = threadIdx.x;
  const int wid = tid >> 6;                // 0..3
  const int lane = tid & 63;
  const int l15 = lane & 15, l4 = lane >> 4;
  const int jj = 16 * wid + l15;           // e1 gate-tile column
  const size_t s0 = (size_t)blockIdx.x * 32;
  const int egrp = wid >> 1;               // e2 row group handled by this wave
  const int ecol = wid & 1;                // e2 col-tile (0..1)
  const int jj2 = 16 * ecol + l15;         // e2 hidden col (valid < 24)
  const int rb2 = 16 * egrp;               // e2 LDS row base

  const bf16x8* f1 = (const bf16x8*)bf1u;
  const bf16x8* f2 = (const bf16x8*)bf2u;
  bf16x8 b1H[16], b1L[16];                 // e1 frags [g*4+s] (shared by streams)
  #pragma unroll
  for (int g = 0; g < 4; ++g)
    #pragma unroll
    for (int s = 0; s < 4; ++s){
      size_t idx = (size_t)(((wid + 4 * g) * 4 + s) * 64 + lane);
      b1H[g * 4 + s] = f1[2 * idx];
      b1L[g * 4 + s] = f1[2 * idx + 1];
    }
  bf16x8 b2H[12], b2L[12];                 // e2 frags [g*3+s]
  #pragma unroll
  for (int g = 0; g < 4; ++g)
    #pragma unroll
    for (int s = 0; s < 3; ++s){
      size_t idx = (size_t)(((ecol + 2 * g) * 3 + s) * 64 + lane);
      b2H[g * 3 + s] = f2[2 * idx];
      b2L[g * 3 + s] = f2[2 * idx + 1];
    }

  f32x4 init1[4], init2[4];
  #pragma unroll
  for (int g = 0; g < 4; ++g){
    float b = e1_bih[g * 64 + jj] + e1_bhh[g * 64 + jj];
    init1[g] = (f32x4){b, b, b, b};
    float b2 = 0.0f;
    if (jj2 < 24) b2 = e2_bih[g * 24 + jj2] + e2_bhh[g * 24 + jj2];
    init2[g] = (f32x4){b2, b2, b2, b2};
  }

  for (int i = tid; i < 32 * SA1; i += 256){ A1H[0][i] = 0; A1H[1][i] = 0; }
  for (int i = tid; i < 32 * SA2; i += 256){ A2H[0][i] = 0; A2H[1][i] = 0; }
  __syncthreads();
  #pragma unroll
  for (int it = 0; it < 8; ++it){           // stage x_0 (32 rows, all threads)
    int idx = tid + it * 256, row = idx >> 6, k = idx & 63;
    float v = (k < 51) ? xseq[((s0 + row) * T_ + 0) * 51 + k] : 0.0f;
    A1H[0][row * SA1 + k] = f2bf(v);
  }
  __syncthreads();

  float xsA[8], xsB[8];
  #pragma unroll
  for (int it = 0; it < 8; ++it){           // prefetch x_1, x_2
    int idx = tid + it * 256, row = idx >> 6, k = idx & 63;
    xsA[it] = (k < 51) ? xseq[((s0 + row) * T_ + 1) * 51 + k] : 0.0f;
    xsB[it] = (k < 51) ? xseq[((s0 + row) * T_ + 2) * 51 + k] : 0.0f;
  }
  float cc1a[4] = {0.f,0.f,0.f,0.f}, cc1b[4] = {0.f,0.f,0.f,0.f};
  float cc2[4]  = {0.f,0.f,0.f,0.f};

#define ENC_STEP(TCUR, BSEL, XW)                                               \
  {                                                                            \
    const int t = (TCUR);                                                      \
    bf16x8 a1a[4], a1b[4], a2H[3];                                             \
    if (t < T_){                                                               \
      _Pragma("unroll")                                                        \
      for (int s = 0; s < 4; ++s){                                             \
        a1a[s] = *(const bf16x8*)&A1H[BSEL][l15 * SA1 + 32 * s + 8 * l4];      \
        a1b[s] = *(const bf16x8*)&A1H[BSEL][(16 + l15) * SA1 + 32 * s + 8 * l4]; \
      }                                                                        \
    }                                                                          \
    if (t >= 1 && t <= T_){                                                    \
      _Pragma("unroll")                                                        \
      for (int s = 0; s < 3; ++s)                                              \
        a2H[s] = *(const bf16x8*)&A2H[BSEL][(rb2 + l15) * SA2 + 32 * s + 8 * l4]; \
    }                                                                          \
    if (t < T_){  /* e1 step t: both row groups on every wave */               \
      f32x4 accA[4], accB[4];                                                  \
      _Pragma("unroll")                                                        \
      for (int g = 0; g < 4; ++g){                                             \
        accA[g] = dot2<4>(a1a, &b1H[g * 4], &b1L[g * 4], init1[g]);            \
        accB[g] = dot2<4>(a1b, &b1H[g * 4], &b1L[g * 4], init1[g]);            \
      }                                                                        \
      float hvA[4], hvB[4]; unsigned short hA[4], hB[4];                       \
      pw(accA, cc1a, hvA, hA);                                                 \
      pw(accB, cc1b, hvB, hB);                                                 \
      _Pragma("unroll")                                                        \
      for (int r = 0; r < 4; ++r){                                             \
        int rwA = 4 * l4 + r, rwB = 16 + 4 * l4 + r;                           \
        A1H[BSEL ^ 1][rwA * SA1 + 64 + jj] = hA[r];                            \
        A2H[BSEL ^ 1][rwA * SA2 + jj] = hA[r];                                 \
        A1H[BSEL ^ 1][rwB * SA1 + 64 + jj] = hB[r];                            \
        A2H[BSEL ^ 1][rwB * SA2 + jj] = hB[r];                                 \
      }                                                                        \
      if (t + 1 < T_){  /* x_{t+1} -> LDS, prefetch x_{t+3} (all threads) */   \
        _Pragma("unroll")                                                      \
        for (int it = 0; it < 8; it += 2){                                     \
          int idx = tid + it * 256;                                            \
          int row0_ = idx >> 6, k0_ = idx & 63;                                \
          int row1_ = (idx + 256) >> 6, k1_ = (idx + 256) & 63;                \
          unsigned int u = pk2bf(XW[it], XW[it + 1]);                          \
          A1H[BSEL ^ 1][row0_ * SA1 + k0_] = (unsigned short)u;                \
          A1H[BSEL ^ 1][row1_ * SA1 + k1_] = (unsigned short)(u >> 16);        \
        }                                                                      \
        if (t + 3 < T_){                                                       \
          _Pragma("unroll")                                                    \
          for (int it = 0; it < 8; ++it){                                      \
            int idx = tid + it * 256, row = idx >> 6, k = idx & 63;            \
            XW[it] = (k < 51) ? xseq[((s0 + row) * T_ + (t + 3)) * 51 + k] : 0.0f; \
          }                                                                    \
        }                                                                      \
      }                                                                        \
    }                                                                          \
    if (t >= 1 && t <= T_){  /* e2 computes h2_{t-1} for group egrp */         \
      f32x4 acc[4];                                                            \
      _Pragma("unroll")                                                        \
      for (int g = 0; g < 4; ++g)                                              \
        acc[g] = dot2<3>(a2H, &b2H[g * 3], &b2L[g * 3], init2[g]);             \
      float hv[4]; unsigned short hH[4];                                       \
      pw(acc, cc2, hv, hH);                                                    \
      if (jj2 < 24){                                                           \
        _Pragma("unroll")                                                      \
        for (int r = 0; r < 4; ++r)                                            \
          A2H[BSEL ^ 1][(rb2 + 4 * l4 + r) * SA2 + 64 + jj2] = hH[r];          \
        if (t == T_){                                                          \
          _Pragma("unroll")                                                    \
          for (int r = 0; r < 4; ++r)                                          \
            zout[(s0 + rb2 + 4 * l4 + r) * 24 + jj2] = hv[r];                  \
        }                                                                      \
      }                                                                        \
    }                                                                          \
    asm volatile("s_waitcnt lgkmcnt(0)\n\ts_barrier" ::: "memory");            \
  }

  #pragma unroll 1
  for (int tt = 0; tt < 102; tt += 2){
    ENC_STEP(tt,     0, xsA)
    ENC_STEP(tt + 1, 1, xsB)
  }
#undef ENC_STEP
}

// ---------------------------------------------------------------------------
// F2: fused decoder (d1 + d2 + proj), ILP-2: 32 rows/block, 256 threads,
// every wave runs all roles for BOTH row groups.
// Step t: d1 h3_t (t<=99); d2 h4_{t-1} (1<=t<=100); proj of h4_{t-2} (t>=2).
// ---------------------------------------------------------------------------
__global__ __launch_bounds__(256, 1) void fused_dec(
    const float* __restrict__ gxin,
    const unsigned short* __restrict__ bf3u,
    const unsigned short* __restrict__ bf4u,
    const unsigned short* __restrict__ bfpu,
    const float* __restrict__ d2_bih, const float* __restrict__ d2_bhh,
    const float* __restrict__ b_out,
    float* out)
{
  constexpr int SA3 = 72;                  // A3: h3(64) pad
  constexpr int SA4 = 136;                 // A4: h3(64)|h4(64) pad
  __shared__ __align__(16) unsigned short A3H[2][32 * SA3];
  __shared__ __align__(16) unsigned short A4H[2][32 * SA4];

  const int tid = threadIdx.x;
  const int wid = tid >> 6;
  const int lane = tid & 63;
  const int l15 = lane & 15, l4 = lane >> 4;
  const int jj = 16 * wid + l15;
  const size_t s0 = (size_t)blockIdx.x * 32;

  const bf16x8* f3 = (const bf16x8*)bf3u;
  const bf16x8* f4 = (const bf16x8*)bf4u;
  const bf16x8* fp = (const bf16x8*)bfpu;
  bf16x8 b3H[8], b3L[8];                   // d1 [g*2+s]
  bf16x8 b4H[16], b4L[16];                 // d2 [g*4+s]
  bf16x8 bpH[2], bpL[2];                   // proj [s]
  #pragma unroll
  for (int g = 0; g < 4; ++g){
    #pragma unroll
    for (int s = 0; s < 2; ++s){
      size_t idx = (size_t)(((wid + 4 * g) * 2 + s) * 64 + lane);
      b3H[g * 2 + s] = f3[2 * idx];
      b3L[g * 2 + s] = f3[2 * idx + 1];
    }
    #pragma unroll
    for (int s = 0; s < 4; ++s){
      size_t idx = (size_t)(((wid + 4 * g) * 4 + s) * 64 + lane);
      b4H[g * 4 + s] = f4[2 * idx];
      b4L[g * 4 + s] = f4[2 * idx + 1];
    }
  }
  #pragma unroll
  for (int s = 0; s < 2; ++s){
    size_t idx = (size_t)((wid * 2 + s) * 64 + lane);
    bpH[s] = fp[2 * idx];
    bpL[s] = fp[2 * idx + 1];
  }

  f32x4 init3a[4], init3b[4], init4[4];
  #pragma unroll
  for (int g = 0; g < 4; ++g){
    #pragma unroll
    for (int r = 0; r < 4; ++r){
      init3a[g][r] = gxin[(s0 + 4 * l4 + r) * 256 + jj + 64 * g];
      init3b[g][r] = gxin[(s0 + 16 + 4 * l4 + r) * 256 + jj + 64 * g];
    }
    float b = d2_bih[g * 64 + jj] + d2_bhh[g * 64 + jj];
    init4[g] = (f32x4){b, b, b, b};
  }
  float bp = (jj < 51) ? b_out[jj] : 0.0f;
  const f32x4 biasP = (f32x4){bp, bp, bp, bp};

  for (int i = tid; i < 32 * SA3; i += 256){ A3H[0][i] = 0; A3H[1][i] = 0; }
  for (int i = tid; i < 32 * SA4; i += 256){ A4H[0][i] = 0; A4H[1][i] = 0; }
  __syncthreads();

  float cc3a[4] = {0.f,0.f,0.f,0.f}, cc3b[4] = {0.f,0.f,0.f,0.f};
  float cc4a[4] = {0.f,0.f,0.f,0.f}, cc4b[4] = {0.f,0.f,0.f,0.f};

#define DEC_STEP(TCUR, BSEL)                                                   \
  {                                                                            \
    const int t = (TCUR);                                                      \
    bf16x8 a3a[2], a3b[2], a4a[4], a4b[4];                                     \
    if (t < T_){                                                               \
      _Pragma("unroll")                                                        \
      for (int s = 0; s < 2; ++s){                                             \
        a3a[s] = *(const bf16x8*)&A3H[BSEL][l15 * SA3 + 32 * s + 8 * l4];      \
        a3b[s] = *(const bf16x8*)&A3H[BSEL][(16 + l15) * SA3 + 32 * s + 8 * l4]; \
      }                                                                        \
    }                                                                          \
    if (t >= 1){                                                               \
      _Pragma("unroll")                                                        \
      for (int s = 0; s < 4; ++s){                                             \
        a4a[s] = *(const bf16x8*)&A4H[BSEL][l15 * SA4 + 32 * s + 8 * l4];      \
        a4b[s] = *(const bf16x8*)&A4H[BSEL][(16 + l15) * SA4 + 32 * s + 8 * l4]; \
      }                                                                        \
    }                                                                          \
    if (t < T_){  /* d1 step t, both groups */                                 \
      f32x4 accA[4], accB[4];                                                  \
      _Pragma("unroll")                                                        \
      for (int g = 0; g < 4; ++g){                                             \
        accA[g] = dot2<2>(a3a, &b3H[g * 2], &b3L[g * 2], init3a[g]);           \
        accB[g] = dot2<2>(a3b, &b3H[g * 2], &b3L[g * 2], init3b[g]);           \
      }                                                                        \
      float hvA[4], hvB[4]; unsigned short hA[4], hB[4];                       \
      pw(accA, cc3a, hvA, hA);                                                 \
      pw(accB, cc3b, hvB, hB);                                                 \
      _Pragma("unroll")                                                        \
      for (int r = 0; r < 4; ++r){                                             \
        int rwA = 4 * l4 + r, rwB = 16 + 4 * l4 + r;                           \
        A3H[BSEL ^ 1][rwA * SA3 + jj] = hA[r];                                 \
        A4H[BSEL ^ 1][rwA * SA4 + jj] = hA[r];                                 \
        A3H[BSEL ^ 1][rwB * SA3 + jj] = hB[r];                                 \
        A4H[BSEL ^ 1][rwB * SA4 + jj] = hB[r];                                 \
      }                                                                        \
    }                                                                          \
    if (t >= 1 && t <= T_){  /* d2 computes h4_{t-1}, both groups */           \
      f32x4 accA[4], accB[4];                                                  \
      _Pragma("unroll")                                                        \
      for (int g = 0; g < 4; ++g){                                             \
        accA[g] = dot2<4>(a4a, &b4H[g * 4], &b4L[g * 4], init4[g]);            \
        accB[g] = dot2<4>(a4b, &b4H[g * 4], &b4L[g * 4], init4[g]);            \
      }                                                                        \
      float hvA[4], hvB[4]; unsigned short hA[4], hB[4];                       \
      pw(accA, cc4a, hvA, hA);                                                 \
      pw(accB, cc4b, hvB, hB);                                                 \
      _Pragma("unroll")                                                        \
      for (int r = 0; r < 4; ++r){                                             \
        A4H[BSEL ^ 1][(4 * l4 + r) * SA4 + 64 + jj] = hA[r];                   \
        A4H[BSEL ^ 1][(16 + 4 * l4 + r) * SA4 + 64 + jj] = hB[r];              \
      }                                                                        \
    }                                                                          \
    if (t >= 2){  /* proj of h4_{t-2}, both groups (h-section = a4*[2..3]) */  \
      f32x4 prA = dot2<2>(&a4a[2], bpH, bpL, biasP);                           \
      f32x4 prB = dot2<2>(&a4b[2], bpH, bpL, biasP);                           \
      if (jj < 51){                                                            \
        _Pragma("unroll")                                                      \
        for (int r = 0; r < 4; ++r){                                           \
          out[((s0 + 4 * l4 + r) * T_ + (t - 2)) * 51 + jj] = prA[r];          \
          out[((s0 + 16 + 4 * l4 + r) * T_ + (t - 2)) * 51 + jj] = prB[r];     \
        }                                                                      \
      }                                                                        \
    }                                                                          \
    asm volatile("s_waitcnt lgkmcnt(0)\n\ts_barrier" ::: "memory");            \
  }

  #pragma unroll 1
  for (int tt = 0; tt < 102; tt += 2){
    DEC_STEP(tt,     0)
    DEC_STEP(tt + 1, 1)
  }
#undef DEC_STEP
}

extern "C" void kernel_launch(void* const* d_in, const int* in_sizes, int n_in,
                              void* d_out, int out_size, void* d_ws, size_t ws_size,
                              hipStream_t stream)
{
  (void)in_sizes; (void)n_in; (void)out_size; (void)ws_size;
  const float* x      = (const float*)d_in[0];
  const float* e1_wih = (const float*)d_in[1];
  const float* e1_whh = (const float*)d_in[2];
  const float* e1_bih = (const float*)d_in[3];
  const float* e1_bhh = (const float*)d_in[4];
  const float* e2_wih = (const float*)d_in[5];
  const float* e2_whh = (const float*)d_in[6];
  const float* e2_bih = (const float*)d_in[7];
  const float* e2_bhh = (const float*)d_in[8];
  const float* d1_wih = (const float*)d_in[9];
  const float* d1_whh = (const float*)d_in[10];
  const float* d1_bih = (const float*)d_in[11];
  const float* d1_bhh = (const float*)d_in[12];
  const float* d2_wih = (const float*)d_in[13];
  const float* d2_whh = (const float*)d_in[14];
  const float* d2_bih = (const float*)d_in[15];
  const float* d2_bhh = (const float*)d_in[16];
  const float* w_out  = (const float*)d_in[17];
  const float* b_out  = (const float*)d_in[18];

  char* ws = (char*)d_ws;
  unsigned short* bfrag = (unsigned short*)ws;                   // 393,216 B
  const size_t BF_L2 = 131072, BF_L3 = 180224, BF_L4 = 245760, BF_PR = 376832;
  float* zbuf  = (float*)(ws + 393216);                          // 196,608 B
  float* gxbuf = (float*)(ws + 393216 + 196608);                 // 2,097,152 B

  prep_frags<<<96, 256, 0, stream>>>(e1_wih, e1_whh, e2_wih, e2_whh,
                                     d1_whh, d2_wih, d2_whh, w_out, bfrag);
  // F1: x -> (e1 -> e2, fused, ILP-2) -> z[B,24]
  fused_enc<<<64, 256, 0, stream>>>(
      x, bfrag, bfrag + BF_L2 / 2, e1_bih, e1_bhh, e2_bih, e2_bhh, zbuf);
  // decoder-1 constant input contribution (exact fp32)
  gx_k<<<2048, 256, 0, stream>>>(zbuf, d1_wih, d1_bih, d1_bhh, gxbuf);
  // F2: gx -> (d1 -> d2 -> proj, fused, ILP-2) -> recon[B,T,51] fp32
  fused_dec<<<64, 256, 0, stream>>>(
      gxbuf, bfrag + BF_L3 / 2, bfrag + BF_L4 / 2, bfrag + BF_PR / 2,
      d2_bih, d2_bhh, b_out, (float*)d_out);
}

// Round 10
// 224.443 us; speedup vs baseline: 6.9281x; 2.3900x over previous
//
#include <hip/hip_runtime.h>
#include <stdint.h>

typedef __attribute__((ext_vector_type(8))) __bf16 bf16x8;
typedef __attribute__((ext_vector_type(4))) float f32x4;
typedef __attribute__((ext_vector_type(4))) unsigned int uint4v;

#define DI __device__ __forceinline__
#define MFMA_(a,b,c) __builtin_amdgcn_mfma_f32_16x16x32_bf16(a,b,c,0,0,0)

static constexpr int B_ = 2048;
static constexpr int T_ = 100;

DI float bf2f(unsigned short u){
  unsigned int i = ((unsigned int)u) << 16;
  float f; __builtin_memcpy(&f, &i, 4); return f;
}
DI unsigned short f2bf(float f){
  unsigned int x; __builtin_memcpy(&x, &f, 4);
  unsigned int r = (x + 0x7fffu + ((x >> 16) & 1u)) >> 16;
  return (unsigned short)r;
}
// HW packed rounding: D[15:0]=bf16(a), D[31:16]=bf16(b). RNE.
DI unsigned int pk2bf(float a, float b){
  unsigned int r;
  asm("v_cvt_pk_bf16_f32 %0, %1, %2" : "=v"(r) : "v"(a), "v"(b));
  return r;
}
DI float rcp_(float x){ return __builtin_amdgcn_rcpf(x); }
DI float sig_(float x){ return rcp_(1.0f + __expf(-x)); }
DI float tanh_(float x){ return 1.0f - 2.0f * rcp_(__expf(2.0f * x) + 1.0f); }

// Plain bf16 MFMA dot (single accumulator chain).
template<int KS>
DI f32x4 dot1(const bf16x8* a, const bf16x8* b, f32x4 acc)
{
  #pragma unroll
  for (int s = 0; s < KS; ++s)
    acc = MFMA_(a[s], b[s], acc);
  return acc;
}

// LSTM pointwise: gates i,f,g,o -> c,h; h rounded to bf16 via cvt_pk.
DI void pw(const f32x4 (&acc)[4], float (&cc)[4], float (&hv)[4],
           unsigned short (&hH)[4])
{
  #pragma unroll
  for (int r = 0; r < 4; ++r){
    float iv = sig_(acc[0][r]);
    float fv = sig_(acc[1][r]);
    float gv = tanh_(acc[2][r]);
    float ov = sig_(acc[3][r]);
    cc[r] = fv * cc[r] + iv * gv;
    hv[r] = ov * tanh_(cc[r]);
  }
  unsigned int u01 = pk2bf(hv[0], hv[1]);
  unsigned int u23 = pk2bf(hv[2], hv[3]);
  hH[0] = (unsigned short)u01; hH[1] = (unsigned short)(u01 >> 16);
  hH[2] = (unsigned short)u23; hH[3] = (unsigned short)(u23 >> 16);
}

// ---------------------------------------------------------------------------
// Pack all weights (fp32 in) into bf16 MFMA B-fragments (hi piece only).
// fid layout: L1(4096) L2(1536) L3(2048) L4(4096) PROJ(512) = 12288 frags.
// B-frag: lane l holds B[k = 32*s + 8*(l>>4) + e][col = 16*n + (l&15)], e=0..7.
// ---------------------------------------------------------------------------
__global__ __launch_bounds__(256) void prep_frags(
    const float* __restrict__ e1_wih, const float* __restrict__ e1_whh,
    const float* __restrict__ e2_wih, const float* __restrict__ e2_whh,
    const float* __restrict__ d1_whh,
    const float* __restrict__ d2_wih, const float* __restrict__ d2_whh,
    const float* __restrict__ w_out,
    unsigned short* __restrict__ dst)
{
  int fid = blockIdx.x * 256 + threadIdx.x;
  if (fid >= 12288) return;
  int layer, local, KS;
  if (fid < 4096)      { layer = 0; local = fid;         KS = 4; }
  else if (fid < 5632) { layer = 1; local = fid - 4096;  KS = 3; }
  else if (fid < 7680) { layer = 2; local = fid - 5632;  KS = 2; }
  else if (fid < 11776){ layer = 3; local = fid - 7680;  KS = 4; }
  else                 { layer = 4; local = fid - 11776; KS = 2; }
  int lane = local & 63;
  int ns = local >> 6;
  int s = ns % KS, n = ns / KS;
  int col = 16 * n + (lane & 15);
  int kb = 32 * s + 8 * (lane >> 4);
  union { unsigned short u[8]; uint4v v; } pk;
  #pragma unroll
  for (int e = 0; e < 8; ++e){
    int k = kb + e;
    float w = 0.0f;
    if (layer == 0){                       // e1: x(51 pad64)|h1(64); K=128, C=256
      if (k < 51) w = e1_wih[col * 51 + k];
      else if (k >= 64) w = e1_whh[col * 64 + (k - 64)];
    } else if (layer == 1){                // e2: h1(64)|h2(24 pad32); K=96, C=128
      int q = col >> 5, jj = col & 31;
      if (jj < 24){
        int r = q * 24 + jj;
        if (k < 64) w = e2_wih[r * 64 + k];
        else if (k < 88) w = e2_whh[r * 24 + (k - 64)];
      }
    } else if (layer == 2){                // d1 recurrent only; K=64, C=256
      w = d1_whh[col * 64 + k];
    } else if (layer == 3){                // d2: h3(64)|h4(64); K=128, C=256
      if (k < 64) w = d2_wih[col * 64 + k];
      else w = d2_whh[col * 64 + (k - 64)];
    } else {                               // proj: K=64, C=64 (51 used)
      if (col < 51) w = w_out[col * 64 + k];
    }
    pk.u[e] = f2bf(w);
  }
  *(uint4v*)(dst + (size_t)fid * 8) = pk.v;
}

// Decoder-1 constant input contribution (exact fp32):
// gx[s][col] = b_ih[col] + b_hh[col] + z[s,:]·W_ih[col,:]
__global__ __launch_bounds__(256) void gx_k(
    const float* __restrict__ z, const float* __restrict__ d1_wih,
    const float* __restrict__ bih, const float* __restrict__ bhh,
    float* __restrict__ gx)
{
  int s = blockIdx.x, col = threadIdx.x;
  float acc = bih[col] + bhh[col];
  #pragma unroll
  for (int k = 0; k < 24; ++k)
    acc += z[s * 24 + k] * d1_wih[col * 24 + k];
  gx[s * 256 + col] = acc;
}

// ---------------------------------------------------------------------------
// F1: fused encoder (e1 + e2), 16 rows/block, 4 waves (r6 structure — per
// r7/r8: 512-thread blocks force 2 waves/SIMD -> 128-VGPR cap -> spills;
// per r9: ILP-2 scales time 2x -> issue-bound -> cut instructions instead).
// Dedup: e2's k0..63 A-fragment = a1H[2..3] (h1, already loaded); A2 holds
// ONLY h2 (32 cols). Weights plain bf16 (dot1).
// ---------------------------------------------------------------------------
__global__ __launch_bounds__(256, 1) void fused_enc(
    const float* xseq,
    const unsigned short* __restrict__ bf1u,
    const unsigned short* __restrict__ bf2u,
    const float* __restrict__ e1_bih, const float* __restrict__ e1_bhh,
    const float* __restrict__ e2_bih, const float* __restrict__ e2_bhh,
    float* __restrict__ zout)
{
  constexpr int SA1 = 136;                 // A1 row stride (ushorts): x(64)|h1(64) pad
  constexpr int SB2 = 40;                  // A2 row stride: h2(24 pad32) + pad
  __shared__ __align__(16) unsigned short A1H[2][16 * SA1];
  __shared__ __align__(16) unsigned short A2B[2][16 * SB2];

  const int tid = threadIdx.x, wid = tid >> 6, lane = tid & 63;
  const int l15 = lane & 15, l4 = lane >> 4;
  const int jj = 16 * wid + l15;
  const size_t s0 = (size_t)blockIdx.x * 16;
  const bool isE2 = (wid < 2);
  const bool isXW = (wid >= 2);
  const int xt = tid - 128;                // 0..127 on staging waves

  const bf16x8* f1 = (const bf16x8*)bf1u;
  const bf16x8* f2 = (const bf16x8*)bf2u;
  bf16x8 b1H[16];                          // e1 frags [g*4+s]
  #pragma unroll
  for (int g = 0; g < 4; ++g)
    #pragma unroll
    for (int s = 0; s < 4; ++s)
      b1H[g * 4 + s] = f1[(size_t)(((wid + 4 * g) * 4 + s) * 64 + lane)];
  bf16x8 b2H[12];                          // e2 frags [g*3+s] (waves 0,1)
  if (isE2){
    #pragma unroll
    for (int g = 0; g < 4; ++g)
      #pragma unroll
      for (int s = 0; s < 3; ++s)
        b2H[g * 3 + s] = f2[(size_t)(((wid + 2 * g) * 3 + s) * 64 + lane)];
  }

  f32x4 init1[4], init2[4];
  #pragma unroll
  for (int g = 0; g < 4; ++g){
    float b = e1_bih[g * 64 + jj] + e1_bhh[g * 64 + jj];
    init1[g] = (f32x4){b, b, b, b};
    float b2 = 0.0f;
    if (isE2 && jj < 24) b2 = e2_bih[g * 24 + jj] + e2_bhh[g * 24 + jj];
    init2[g] = (f32x4){b2, b2, b2, b2};
  }

  for (int i = tid; i < 16 * SA1; i += 256){ A1H[0][i] = 0; A1H[1][i] = 0; }
  for (int i = tid; i < 16 * SB2; i += 256){ A2B[0][i] = 0; A2B[1][i] = 0; }
  __syncthreads();
  #pragma unroll
  for (int it = 0; it < 4; ++it){           // stage x_0 (all threads)
    int idx = tid + it * 256, row = idx >> 6, k = idx & 63;
    float v = (k < 51) ? xseq[((s0 + row) * T_ + 0) * 51 + k] : 0.0f;
    A1H[0][row * SA1 + k] = f2bf(v);
  }
  __syncthreads();

  float xsA[8], xsB[8];
  if (isXW){
    #pragma unroll
    for (int it = 0; it < 8; ++it){         // prefetch x_1, x_2 (waves 2,3)
      int idx = xt + it * 128, row = idx >> 6, k = idx & 63;
      xsA[it] = (k < 51) ? xseq[((s0 + row) * T_ + 1) * 51 + k] : 0.0f;
      xsB[it] = (k < 51) ? xseq[((s0 + row) * T_ + 2) * 51 + k] : 0.0f;
    }
  }
  float cc1[4] = {0.f,0.f,0.f,0.f}, cc2[4] = {0.f,0.f,0.f,0.f};

#define ENC_STEP(TCUR, BSEL, XW)                                               \
  {                                                                            \
    const int t = (TCUR);                                                      \
    bf16x8 a1H[4], a2b;                                                        \
    _Pragma("unroll")                                                          \
    for (int s = 0; s < 4; ++s)                                                \
      a1H[s] = *(const bf16x8*)&A1H[BSEL][l15 * SA1 + 32 * s + 8 * l4];        \
    if (isE2 && t >= 1)                                                        \
      a2b = *(const bf16x8*)&A2B[BSEL][l15 * SB2 + 8 * l4];                    \
    if (t < T_){  /* e1 step t: all waves */                                   \
      f32x4 acc[4];                                                            \
      _Pragma("unroll")                                                        \
      for (int g = 0; g < 4; ++g)                                              \
        acc[g] = dot1<4>(a1H, &b1H[g * 4], init1[g]);                          \
      float hv[4]; unsigned short hH[4];                                       \
      pw(acc, cc1, hv, hH);                                                    \
      _Pragma("unroll")                                                        \
      for (int r = 0; r < 4; ++r)                                              \
        A1H[BSEL ^ 1][(4 * l4 + r) * SA1 + 64 + jj] = hH[r];                   \
      if (isXW && t + 1 < T_){  /* x_{t+1} -> LDS, prefetch x_{t+3} */         \
        _Pragma("unroll")                                                      \
        for (int it = 0; it < 8; it += 2){                                     \
          int idx = xt + it * 128;                                             \
          int row0_ = idx >> 6, k0_ = idx & 63;                                \
          int row1_ = (idx + 128) >> 6, k1_ = (idx + 128) & 63;                \
          unsigned int u = pk2bf(XW[it], XW[it + 1]);                          \
          A1H[BSEL ^ 1][row0_ * SA1 + k0_] = (unsigned short)u;                \
          A1H[BSEL ^ 1][row1_ * SA1 + k1_] = (unsigned short)(u >> 16);        \
        }                                                                      \
        if (t + 3 < T_){                                                       \
          _Pragma("unroll")                                                    \
          for (int it = 0; it < 8; ++it){                                      \
            int idx = xt + it * 128, row = idx >> 6, k = idx & 63;             \
            XW[it] = (k < 51) ? xseq[((s0 + row) * T_ + (t + 3)) * 51 + k] : 0.0f; \
          }                                                                    \
        }                                                                      \
      }                                                                        \
    }                                                                          \
    if (isE2 && t >= 1 && t <= T_){  /* e2 computes h2_{t-1}: waves 0,1 */     \
      bf16x8 af2[3] = { a1H[2], a1H[3], a2b };  /* h1 | h2 */                  \
      f32x4 acc[4];                                                            \
      _Pragma("unroll")                                                        \
      for (int g = 0; g < 4; ++g)                                              \
        acc[g] = dot1<3>(af2, &b2H[g * 3], init2[g]);                          \
      float hv[4]; unsigned short hH[4];                                       \
      pw(acc, cc2, hv, hH);                                                    \
      if (jj < 24){                                                            \
        _Pragma("unroll")                                                      \
        for (int r = 0; r < 4; ++r)                                            \
          A2B[BSEL ^ 1][(4 * l4 + r) * SB2 + jj] = hH[r];                      \
        if (t == T_){                                                          \
          _Pragma("unroll")                                                    \
          for (int r = 0; r < 4; ++r)                                          \
            zout[(s0 + 4 * l4 + r) * 24 + jj] = hv[r];                         \
        }                                                                      \
      }                                                                        \
    }                                                                          \
    asm volatile("s_waitcnt lgkmcnt(0)\n\ts_barrier" ::: "memory");            \
  }

  #pragma unroll 1
  for (int tt = 0; tt < 102; tt += 2){
    ENC_STEP(tt,     0, xsA)
    ENC_STEP(tt + 1, 1, xsB)
  }
#undef ENC_STEP
}

// ---------------------------------------------------------------------------
// F2: fused decoder (d1 + d2 + proj), 16 rows/block, 4 waves.
// Single A4 state tile [h3(64)|h4(64)]: d1's A-fragment = a4[0..1] (shared
// with d2), proj's = a4[2..3] — one set of 4 ds_reads serves all 3 layers.
// Step t: d1 h3_t (t<=99); d2 h4_{t-1} (1<=t<=100); proj h4_{t-2} (t>=2).
// ---------------------------------------------------------------------------
__global__ __launch_bounds__(256, 1) void fused_dec(
    const float* __restrict__ gxin,
    const unsigned short* __restrict__ bf3u,
    const unsigned short* __restrict__ bf4u,
    const unsigned short* __restrict__ bfpu,
    const float* __restrict__ d2_bih, const float* __restrict__ d2_bhh,
    const float* __restrict__ b_out,
    float* out)
{
  constexpr int SA4 = 136;                 // A4: h3(64)|h4(64) pad
  __shared__ __align__(16) unsigned short A4H[2][16 * SA4];

  const int tid = threadIdx.x, wid = tid >> 6, lane = tid & 63;
  const int l15 = lane & 15, l4 = lane >> 4;
  const int jj = 16 * wid + l15;
  const size_t s0 = (size_t)blockIdx.x * 16;

  const bf16x8* f3 = (const bf16x8*)bf3u;
  const bf16x8* f4 = (const bf16x8*)bf4u;
  const bf16x8* fp = (const bf16x8*)bfpu;
  bf16x8 b3H[8], b4H[16], bpH[2];
  #pragma unroll
  for (int g = 0; g < 4; ++g){
    #pragma unroll
    for (int s = 0; s < 2; ++s)
      b3H[g * 2 + s] = f3[(size_t)(((wid + 4 * g) * 2 + s) * 64 + lane)];
    #pragma unroll
    for (int s = 0; s < 4; ++s)
      b4H[g * 4 + s] = f4[(size_t)(((wid + 4 * g) * 4 + s) * 64 + lane)];
  }
  #pragma unroll
  for (int s = 0; s < 2; ++s)
    bpH[s] = fp[(size_t)((wid * 2 + s) * 64 + lane)];

  f32x4 init3[4], init4[4];
  #pragma unroll
  for (int g = 0; g < 4; ++g){
    #pragma unroll
    for (int r = 0; r < 4; ++r)
      init3[g][r] = gxin[(s0 + 4 * l4 + r) * 256 + jj + 64 * g];
    float b = d2_bih[g * 64 + jj] + d2_bhh[g * 64 + jj];
    init4[g] = (f32x4){b, b, b, b};
  }
  float bp = (jj < 51) ? b_out[jj] : 0.0f;
  const f32x4 biasP = (f32x4){bp, bp, bp, bp};

  for (int i = tid; i < 16 * SA4; i += 256){ A4H[0][i] = 0; A4H[1][i] = 0; }
  __syncthreads();

  float cc3[4] = {0.f,0.f,0.f,0.f}, cc4[4] = {0.f,0.f,0.f,0.f};

#define DEC_STEP(TCUR, BSEL)                                                   \
  {                                                                            \
    const int t = (TCUR);                                                      \
    bf16x8 a4[4];                                                              \
    _Pragma("unroll")                                                          \
    for (int s = 0; s < 4; ++s)                                                \
      a4[s] = *(const bf16x8*)&A4H[BSEL][l15 * SA4 + 32 * s + 8 * l4];         \
    if (t < T_){  /* d1 step t (A-frag = h3 section = a4[0..1]) */             \
      f32x4 acc[4];                                                            \
      _Pragma("unroll")                                                        \
      for (int g = 0; g < 4; ++g)                                              \
        acc[g] = dot1<2>(a4, &b3H[g * 2], init3[g]);                           \
      float hv[4]; unsigned short hH[4];                                       \
      pw(acc, cc3, hv, hH);                                                    \
      _Pragma("unroll")                                                        \
      for (int r = 0; r < 4; ++r)                                              \
        A4H[BSEL ^ 1][(4 * l4 + r) * SA4 + jj] = hH[r];                        \
    }                                                                          \
    if (t >= 1 && t <= T_){  /* d2 computes h4_{t-1} */                        \
      f32x4 acc[4];                                                            \
      _Pragma("unroll")                                                        \
      for (int g = 0; g < 4; ++g)                                              \
        acc[g] = dot1<4>(a4, &b4H[g * 4], init4[g]);                           \
      float hv[4]; unsigned short hH[4];                                       \
      pw(acc, cc4, hv, hH);                                                    \
      _Pragma("unroll")                                                        \
      for (int r = 0; r < 4; ++r)                                              \
        A4H[BSEL ^ 1][(4 * l4 + r) * SA4 + 64 + jj] = hH[r];                   \
    }                                                                          \
    if (t >= 2){  /* proj of h4_{t-2} (= a4[2..3]) */                          \
      f32x4 pr = dot1<2>(&a4[2], bpH, biasP);                                  \
      if (jj < 51){                                                            \
        _Pragma("unroll")                                                      \
        for (int r = 0; r < 4; ++r)                                            \
          out[((s0 + 4 * l4 + r) * T_ + (t - 2)) * 51 + jj] = pr[r];           \
      }                                                                        \
    }                                                                          \
    asm volatile("s_waitcnt lgkmcnt(0)\n\ts_barrier" ::: "memory");            \
  }

  #pragma unroll 1
  for (int tt = 0; tt < 102; tt += 2){
    DEC_STEP(tt,     0)
    DEC_STEP(tt + 1, 1)
  }
#undef DEC_STEP
}

extern "C" void kernel_launch(void* const* d_in, const int* in_sizes, int n_in,
                              void* d_out, int out_size, void* d_ws, size_t ws_size,
                              hipStream_t stream)
{
  (void)in_sizes; (void)n_in; (void)out_size; (void)ws_size;
  const float* x      = (const float*)d_in[0];
  const float* e1_wih = (const float*)d_in[1];
  const float* e1_whh = (const float*)d_in[2];
  const float* e1_bih = (const float*)d_in[3];
  const float* e1_bhh = (const float*)d_in[4];
  const float* e2_wih = (const float*)d_in[5];
  const float* e2_whh = (const float*)d_in[6];
  const float* e2_bih = (const float*)d_in[7];
  const float* e2_bhh = (const float*)d_in[8];
  const float* d1_wih = (const float*)d_in[9];
  const float* d1_whh = (const float*)d_in[10];
  const float* d1_bih = (const float*)d_in[11];
  const float* d1_bhh = (const float*)d_in[12];
  const float* d2_wih = (const float*)d_in[13];
  const float* d2_whh = (const float*)d_in[14];
  const float* d2_bih = (const float*)d_in[15];
  const float* d2_bhh = (const float*)d_in[16];
  const float* w_out  = (const float*)d_in[17];
  const float* b_out  = (const float*)d_in[18];

  char* ws = (char*)d_ws;
  unsigned short* bfrag = (unsigned short*)ws;                   // 196,608 B
  // fragment element offsets (ushorts, fid*8)
  const size_t OF_L2 = 4096 * 8, OF_L3 = 5632 * 8, OF_L4 = 7680 * 8, OF_PR = 11776 * 8;
  float* zbuf  = (float*)(ws + 196608);                          // 196,608 B
  float* gxbuf = (float*)(ws + 196608 + 196608);                 // 2,097,152 B

  prep_frags<<<48, 256, 0, stream>>>(e1_wih, e1_whh, e2_wih, e2_whh,
                                     d1_whh, d2_wih, d2_whh, w_out, bfrag);
  // F1: x -> (e1 -> e2, fused) -> z[B,24]
  fused_enc<<<128, 256, 0, stream>>>(
      x, bfrag, bfrag + OF_L2, e1_bih, e1_bhh, e2_bih, e2_bhh, zbuf);
  // decoder-1 constant input contribution (exact fp32)
  gx_k<<<2048, 256, 0, stream>>>(zbuf, d1_wih, d1_bih, d1_bhh, gxbuf);
  // F2: gx -> (d1 -> d2 -> proj, fused) -> recon[B,T,51] fp32
  fused_dec<<<128, 256, 0, stream>>>(
      gxbuf, bfrag + OF_L3, bfrag + OF_L4, bfrag + OF_PR,
      d2_bih, d2_bhh, b_out, (float*)d_out);
}

// Round 11
// 172.582 us; speedup vs baseline: 9.0100x; 1.3005x over previous
//
#include <hip/hip_runtime.h>
#include <stdint.h>

typedef __attribute__((ext_vector_type(8))) __bf16 bf16x8;
typedef __attribute__((ext_vector_type(4))) float f32x4;
typedef __attribute__((ext_vector_type(4))) unsigned int uint4v;

#define DI __device__ __forceinline__
#define MFMA_(a,b,c) __builtin_amdgcn_mfma_f32_16x16x32_bf16(a,b,c,0,0,0)

static constexpr int B_ = 2048;
static constexpr int T_ = 100;

DI float bf2f(unsigned short u){
  unsigned int i = ((unsigned int)u) << 16;
  float f; __builtin_memcpy(&f, &i, 4); return f;
}
DI unsigned short f2bf(float f){
  unsigned int x; __builtin_memcpy(&x, &f, 4);
  unsigned int r = (x + 0x7fffu + ((x >> 16) & 1u)) >> 16;
  return (unsigned short)r;
}
// HW packed rounding: D[15:0]=bf16(a), D[31:16]=bf16(b). RNE.
DI unsigned int pk2bf(float a, float b){
  unsigned int r;
  asm("v_cvt_pk_bf16_f32 %0, %1, %2" : "=v"(r) : "v"(a), "v"(b));
  return r;
}
DI float rcp_(float x){ return __builtin_amdgcn_rcpf(x); }
DI float sig_(float x){ return rcp_(1.0f + __expf(-x)); }
DI float tanh_(float x){ return 1.0f - 2.0f * rcp_(__expf(2.0f * x) + 1.0f); }

// Plain bf16 MFMA dot (single accumulator chain).
template<int KS>
DI f32x4 dot1(const bf16x8* a, const bf16x8* b, f32x4 acc)
{
  #pragma unroll
  for (int s = 0; s < KS; ++s)
    acc = MFMA_(a[s], b[s], acc);
  return acc;
}

// LSTM pointwise: gates i,f,g,o -> c,h; h rounded to bf16 via cvt_pk.
DI void pw(const f32x4 (&acc)[4], float (&cc)[4], float (&hv)[4],
           unsigned short (&hH)[4])
{
  #pragma unroll
  for (int r = 0; r < 4; ++r){
    float iv = sig_(acc[0][r]);
    float fv = sig_(acc[1][r]);
    float gv = tanh_(acc[2][r]);
    float ov = sig_(acc[3][r]);
    cc[r] = fv * cc[r] + iv * gv;
    hv[r] = ov * tanh_(cc[r]);
  }
  unsigned int u01 = pk2bf(hv[0], hv[1]);
  unsigned int u23 = pk2bf(hv[2], hv[3]);
  hH[0] = (unsigned short)u01; hH[1] = (unsigned short)(u01 >> 16);
  hH[2] = (unsigned short)u23; hH[3] = (unsigned short)(u23 >> 16);
}

// ---------------------------------------------------------------------------
// Pack all weights (fp32 in) into bf16 MFMA B-fragments.
// fid layout: L1(4096) L2(1536) L3(2048) L4(4096) PROJ(512) = 12288 frags.
// B-frag: lane l holds B[k = 32*s + 8*(l>>4) + e][col = 16*n + (l&15)], e=0..7.
// ---------------------------------------------------------------------------
__global__ __launch_bounds__(256) void prep_frags(
    const float* __restrict__ e1_wih, const float* __restrict__ e1_whh,
    const float* __restrict__ e2_wih, const float* __restrict__ e2_whh,
    const float* __restrict__ d1_whh,
    const float* __restrict__ d2_wih, const float* __restrict__ d2_whh,
    const float* __restrict__ w_out,
    unsigned short* __restrict__ dst)
{
  int fid = blockIdx.x * 256 + threadIdx.x;
  if (fid >= 12288) return;
  int layer, local, KS;
  if (fid < 4096)      { layer = 0; local = fid;         KS = 4; }
  else if (fid < 5632) { layer = 1; local = fid - 4096;  KS = 3; }
  else if (fid < 7680) { layer = 2; local = fid - 5632;  KS = 2; }
  else if (fid < 11776){ layer = 3; local = fid - 7680;  KS = 4; }
  else                 { layer = 4; local = fid - 11776; KS = 2; }
  int lane = local & 63;
  int ns = local >> 6;
  int s = ns % KS, n = ns / KS;
  int col = 16 * n + (lane & 15);
  int kb = 32 * s + 8 * (lane >> 4);
  union { unsigned short u[8]; uint4v v; } pk;
  #pragma unroll
  for (int e = 0; e < 8; ++e){
    int k = kb + e;
    float w = 0.0f;
    if (layer == 0){                       // e1: x(51 pad64)|h1(64); K=128, C=256
      if (k < 51) w = e1_wih[col * 51 + k];
      else if (k >= 64) w = e1_whh[col * 64 + (k - 64)];
    } else if (layer == 1){                // e2: h1(64)|h2(24 pad32); K=96, C=128
      int q = col >> 5, jj = col & 31;
      if (jj < 24){
        int r = q * 24 + jj;
        if (k < 64) w = e2_wih[r * 64 + k];
        else if (k < 88) w = e2_whh[r * 24 + (k - 64)];
      }
    } else if (layer == 2){                // d1 recurrent only; K=64, C=256
      w = d1_whh[col * 64 + k];
    } else if (layer == 3){                // d2: h3(64)|h4(64); K=128, C=256
      if (k < 64) w = d2_wih[col * 64 + k];
      else w = d2_whh[col * 64 + (k - 64)];
    } else {                               // proj: K=64, C=64 (51 used)
      if (col < 51) w = w_out[col * 64 + k];
    }
    pk.u[e] = f2bf(w);
  }
  *(uint4v*)(dst + (size_t)fid * 8) = pk.v;
}

// Decoder-1 constant input contribution (exact fp32):
// gx[s][col] = b_ih[col] + b_hh[col] + z[s,:]·W_ih[col,:]
__global__ __launch_bounds__(256) void gx_k(
    const float* __restrict__ z, const float* __restrict__ d1_wih,
    const float* __restrict__ bih, const float* __restrict__ bhh,
    float* __restrict__ gx)
{
  int s = blockIdx.x, col = threadIdx.x;
  float acc = bih[col] + bhh[col];
  #pragma unroll
  for (int k = 0; k < 24; ++k)
    acc += z[s * 24 + k] * d1_wih[col * 24 + k];
  gx[s * 256 + col] = acc;
}

// ---------------------------------------------------------------------------
// F1: fused encoder, ROLE-SPLIT 8 waves / 512 threads / 16 rows per block.
// waves 0-3: e1 (col-tile wid, 16 MFMA + pw); waves 4-5: e2 (col-tile wid-4,
// 12 MFMA + pw, lag 1); waves 6-7: x staging. Per-role register sets are
// small (dot1) so the 2-waves/SIMD 256-unified-reg cap is satisfied
// (r7/r8's spill was dot2's ~330-reg union). Different-role waves pair on
// each SIMD -> co-issue.
// ---------------------------------------------------------------------------
__global__ __launch_bounds__(512, 1) void fused_enc(
    const float* xseq,
    const unsigned short* __restrict__ bf1u,
    const unsigned short* __restrict__ bf2u,
    const float* __restrict__ e1_bih, const float* __restrict__ e1_bhh,
    const float* __restrict__ e2_bih, const float* __restrict__ e2_bhh,
    float* __restrict__ zout)
{
  constexpr int SA1 = 136;                 // A1 row stride: x(64)|h1(64) pad
  constexpr int SB2 = 40;                  // A2 row stride: h2(24 pad32) + pad
  __shared__ __align__(16) unsigned short A1H[2][16 * SA1];
  __shared__ __align__(16) unsigned short A2B[2][16 * SB2];

  const int tid = threadIdx.x, wid = tid >> 6, lane = tid & 63;
  const int l15 = lane & 15, l4 = lane >> 4;
  const size_t s0 = (size_t)blockIdx.x * 16;
  const bool isE1 = (wid < 4);
  const bool isE2 = (wid == 4 || wid == 5);
  const bool isXW = (wid >= 6);
  const int jj1 = 16 * wid + l15;          // e1 col (wid 0-3)
  const int jj2 = 16 * (wid - 4) + l15;    // e2 col (wid 4-5)
  const int xt = tid - 384;                // 0..127 on staging waves

  const bf16x8* f1 = (const bf16x8*)bf1u;
  const bf16x8* f2 = (const bf16x8*)bf2u;
  bf16x8 b1H[16];                          // e1 frags [g*4+s]
  f32x4 init1[4];
  if (isE1){
    #pragma unroll
    for (int g = 0; g < 4; ++g){
      #pragma unroll
      for (int s = 0; s < 4; ++s)
        b1H[g * 4 + s] = f1[(size_t)(((wid + 4 * g) * 4 + s) * 64 + lane)];
      float b = e1_bih[g * 64 + jj1] + e1_bhh[g * 64 + jj1];
      init1[g] = (f32x4){b, b, b, b};
    }
  }
  bf16x8 b2H[12];                          // e2 frags [g*3+s]
  f32x4 init2[4];
  if (isE2){
    #pragma unroll
    for (int g = 0; g < 4; ++g){
      #pragma unroll
      for (int s = 0; s < 3; ++s)
        b2H[g * 3 + s] = f2[(size_t)((((wid - 4) + 2 * g) * 3 + s) * 64 + lane)];
      float b2 = (jj2 < 24) ? (e2_bih[g * 24 + jj2] + e2_bhh[g * 24 + jj2]) : 0.0f;
      init2[g] = (f32x4){b2, b2, b2, b2};
    }
  }

  for (int i = tid; i < 16 * SA1; i += 512){ A1H[0][i] = 0; A1H[1][i] = 0; }
  for (int i = tid; i < 16 * SB2; i += 512){ A2B[0][i] = 0; A2B[1][i] = 0; }
  __syncthreads();
  #pragma unroll
  for (int it = 0; it < 2; ++it){           // stage x_0 (all 512 threads)
    int idx = tid + it * 512, row = idx >> 6, k = idx & 63;
    float v = (k < 51) ? xseq[((s0 + row) * T_ + 0) * 51 + k] : 0.0f;
    A1H[0][row * SA1 + k] = f2bf(v);
  }
  __syncthreads();

  float xsA[8], xsB[8];
  if (isXW){
    #pragma unroll
    for (int it = 0; it < 8; ++it){         // prefetch x_1, x_2 (waves 6,7)
      int idx = xt + it * 128, row = idx >> 6, k = idx & 63;
      xsA[it] = (k < 51) ? xseq[((s0 + row) * T_ + 1) * 51 + k] : 0.0f;
      xsB[it] = (k < 51) ? xseq[((s0 + row) * T_ + 2) * 51 + k] : 0.0f;
    }
  }
  float cc1[4] = {0.f,0.f,0.f,0.f}, cc2[4] = {0.f,0.f,0.f,0.f};

#define ENC_STEP(TCUR, BSEL, XW)                                               \
  {                                                                            \
    const int t = (TCUR);                                                      \
    if (isE1 && t < T_){  /* e1 step t */                                      \
      bf16x8 a1H[4];                                                           \
      _Pragma("unroll")                                                        \
      for (int s = 0; s < 4; ++s)                                              \
        a1H[s] = *(const bf16x8*)&A1H[BSEL][l15 * SA1 + 32 * s + 8 * l4];      \
      f32x4 acc[4];                                                            \
      _Pragma("unroll")                                                        \
      for (int g = 0; g < 4; ++g)                                              \
        acc[g] = dot1<4>(a1H, &b1H[g * 4], init1[g]);                          \
      float hv[4]; unsigned short hH[4];                                       \
      pw(acc, cc1, hv, hH);                                                    \
      _Pragma("unroll")                                                        \
      for (int r = 0; r < 4; ++r)                                              \
        A1H[BSEL ^ 1][(4 * l4 + r) * SA1 + 64 + jj1] = hH[r];                  \
    }                                                                          \
    if (isE2 && t >= 1 && t <= T_){  /* e2 computes h2_{t-1} */                \
      bf16x8 af2[3];                                                           \
      af2[0] = *(const bf16x8*)&A1H[BSEL][l15 * SA1 + 64 + 8 * l4];            \
      af2[1] = *(const bf16x8*)&A1H[BSEL][l15 * SA1 + 96 + 8 * l4];            \
      af2[2] = *(const bf16x8*)&A2B[BSEL][l15 * SB2 + 8 * l4];                 \
      f32x4 acc[4];                                                            \
      _Pragma("unroll")                                                        \
      for (int g = 0; g < 4; ++g)                                              \
        acc[g] = dot1<3>(af2, &b2H[g * 3], init2[g]);                          \
      float hv[4]; unsigned short hH[4];                                       \
      pw(acc, cc2, hv, hH);                                                    \
      if (jj2 < 24){                                                           \
        _Pragma("unroll")                                                      \
        for (int r = 0; r < 4; ++r)                                            \
          A2B[BSEL ^ 1][(4 * l4 + r) * SB2 + jj2] = hH[r];                     \
        if (t == T_){                                                          \
          _Pragma("unroll")                                                    \
          for (int r = 0; r < 4; ++r)                                          \
            zout[(s0 + 4 * l4 + r) * 24 + jj2] = hv[r];                        \
        }                                                                      \
      }                                                                        \
    }                                                                          \
    if (isXW && t + 1 < T_){  /* x_{t+1} -> LDS, prefetch x_{t+3} */           \
      _Pragma("unroll")                                                        \
      for (int it = 0; it < 8; it += 2){                                       \
        int idx = xt + it * 128;                                               \
        int row0_ = idx >> 6, k0_ = idx & 63;                                  \
        int row1_ = (idx + 128) >> 6, k1_ = (idx + 128) & 63;                  \
        unsigned int u = pk2bf(XW[it], XW[it + 1]);                            \
        A1H[BSEL ^ 1][row0_ * SA1 + k0_] = (unsigned short)u;                  \
        A1H[BSEL ^ 1][row1_ * SA1 + k1_] = (unsigned short)(u >> 16);          \
      }                                                                        \
      if (t + 3 < T_){                                                         \
        _Pragma("unroll")                                                      \
        for (int it = 0; it < 8; ++it){                                        \
          int idx = xt + it * 128, row = idx >> 6, k = idx & 63;               \
          XW[it] = (k < 51) ? xseq[((s0 + row) * T_ + (t + 3)) * 51 + k] : 0.0f; \
        }                                                                      \
      }                                                                        \
    }                                                                          \
    asm volatile("s_waitcnt lgkmcnt(0)\n\ts_barrier" ::: "memory");            \
  }

  #pragma unroll 1
  for (int tt = 0; tt < 102; tt += 2){
    ENC_STEP(tt,     0, xsA)
    ENC_STEP(tt + 1, 1, xsB)
  }
#undef ENC_STEP
}

// ---------------------------------------------------------------------------
// F2: fused decoder, ROLE-SPLIT 8 waves / 512 threads / 16 rows per block.
// waves 0-3: d1 (8 MFMA + pw) + proj (8 MFMA + stores); waves 4-7: d2
// (16 MFMA + pw). Within a step d1/d2/proj are independent (lag structure);
// all share the single A4 [h3|h4] double-buffered state tile.
// ---------------------------------------------------------------------------
__global__ __launch_bounds__(512, 1) void fused_dec(
    const float* __restrict__ gxin,
    const unsigned short* __restrict__ bf3u,
    const unsigned short* __restrict__ bf4u,
    const unsigned short* __restrict__ bfpu,
    const float* __restrict__ d2_bih, const float* __restrict__ d2_bhh,
    const float* __restrict__ b_out,
    float* out)
{
  constexpr int SA4 = 136;                 // A4: h3(64)|h4(64) pad
  __shared__ __align__(16) unsigned short A4H[2][16 * SA4];

  const int tid = threadIdx.x, wid = tid >> 6, lane = tid & 63;
  const int l15 = lane & 15, l4 = lane >> 4;
  const size_t s0 = (size_t)blockIdx.x * 16;
  const bool isD1 = (wid < 4);
  const int jj3 = 16 * wid + l15;          // d1/proj col (wid 0-3)
  const int jj4 = 16 * (wid - 4) + l15;    // d2 col (wid 4-7)

  const bf16x8* f3 = (const bf16x8*)bf3u;
  const bf16x8* f4 = (const bf16x8*)bf4u;
  const bf16x8* fp = (const bf16x8*)bfpu;
  bf16x8 b3H[8], bpH[2];
  f32x4 init3[4], biasP;
  if (isD1){
    #pragma unroll
    for (int g = 0; g < 4; ++g){
      #pragma unroll
      for (int s = 0; s < 2; ++s)
        b3H[g * 2 + s] = f3[(size_t)(((wid + 4 * g) * 2 + s) * 64 + lane)];
      #pragma unroll
      for (int r = 0; r < 4; ++r)
        init3[g][r] = gxin[(s0 + 4 * l4 + r) * 256 + jj3 + 64 * g];
    }
    #pragma unroll
    for (int s = 0; s < 2; ++s)
      bpH[s] = fp[(size_t)((wid * 2 + s) * 64 + lane)];
    float bp = (jj3 < 51) ? b_out[jj3] : 0.0f;
    biasP = (f32x4){bp, bp, bp, bp};
  }
  bf16x8 b4H[16];
  f32x4 init4[4];
  if (!isD1){
    #pragma unroll
    for (int g = 0; g < 4; ++g){
      #pragma unroll
      for (int s = 0; s < 4; ++s)
        b4H[g * 4 + s] = f4[(size_t)((((wid - 4) + 4 * g) * 4 + s) * 64 + lane)];
      float b = d2_bih[g * 64 + jj4] + d2_bhh[g * 64 + jj4];
      init4[g] = (f32x4){b, b, b, b};
    }
  }

  for (int i = tid; i < 16 * SA4; i += 512){ A4H[0][i] = 0; A4H[1][i] = 0; }
  __syncthreads();

  float cc3[4] = {0.f,0.f,0.f,0.f}, cc4[4] = {0.f,0.f,0.f,0.f};

#define DEC_STEP(TCUR, BSEL)                                                   \
  {                                                                            \
    const int t = (TCUR);                                                      \
    bf16x8 a4[4];                                                              \
    _Pragma("unroll")                                                          \
    for (int s = 0; s < 4; ++s)                                                \
      a4[s] = *(const bf16x8*)&A4H[BSEL][l15 * SA4 + 32 * s + 8 * l4];         \
    if (isD1){                                                                 \
      if (t < T_){  /* d1 step t (A-frag = h3 = a4[0..1]) */                   \
        f32x4 acc[4];                                                          \
        _Pragma("unroll")                                                      \
        for (int g = 0; g < 4; ++g)                                            \
          acc[g] = dot1<2>(a4, &b3H[g * 2], init3[g]);                         \
        float hv[4]; unsigned short hH[4];                                     \
        pw(acc, cc3, hv, hH);                                                  \
        _Pragma("unroll")                                                      \
        for (int r = 0; r < 4; ++r)                                            \
          A4H[BSEL ^ 1][(4 * l4 + r) * SA4 + jj3] = hH[r];                     \
      }                                                                        \
      if (t >= 2){  /* proj of h4_{t-2} (= a4[2..3]) */                        \
        f32x4 pr = dot1<2>(&a4[2], bpH, biasP);                                \
        if (jj3 < 51){                                                         \
          _Pragma("unroll")                                                    \
          for (int r = 0; r < 4; ++r)                                          \
            out[((s0 + 4 * l4 + r) * T_ + (t - 2)) * 51 + jj3] = pr[r];        \
        }                                                                      \
      }                                                                        \
    } else {                                                                   \
      if (t >= 1 && t <= T_){  /* d2 computes h4_{t-1} */                      \
        f32x4 acc[4];                                                          \
        _Pragma("unroll")                                                      \
        for (int g = 0; g < 4; ++g)                                            \
          acc[g] = dot1<4>(a4, &b4H[g * 4], init4[g]);                         \
        float hv[4]; unsigned short hH[4];                                     \
        pw(acc, cc4, hv, hH);                                                  \
        _Pragma("unroll")                                                      \
        for (int r = 0; r < 4; ++r)                                            \
          A4H[BSEL ^ 1][(4 * l4 + r) * SA4 + 64 + jj4] = hH[r];                \
      }                                                                        \
    }                                                                          \
    asm volatile("s_waitcnt lgkmcnt(0)\n\ts_barrier" ::: "memory");            \
  }

  #pragma unroll 1
  for (int tt = 0; tt < 102; tt += 2){
    DEC_STEP(tt,     0)
    DEC_STEP(tt + 1, 1)
  }
#undef DEC_STEP
}

extern "C" void kernel_launch(void* const* d_in, const int* in_sizes, int n_in,
                              void* d_out, int out_size, void* d_ws, size_t ws_size,
                              hipStream_t stream)
{
  (void)in_sizes; (void)n_in; (void)out_size; (void)ws_size;
  const float* x      = (const float*)d_in[0];
  const float* e1_wih = (const float*)d_in[1];
  const float* e1_whh = (const float*)d_in[2];
  const float* e1_bih = (const float*)d_in[3];
  const float* e1_bhh = (const float*)d_in[4];
  const float* e2_wih = (const float*)d_in[5];
  const float* e2_whh = (const float*)d_in[6];
  const float* e2_bih = (const float*)d_in[7];
  const float* e2_bhh = (const float*)d_in[8];
  const float* d1_wih = (const float*)d_in[9];
  const float* d1_whh = (const float*)d_in[10];
  const float* d1_bih = (const float*)d_in[11];
  const float* d1_bhh = (const float*)d_in[12];
  const float* d2_wih = (const float*)d_in[13];
  const float* d2_whh = (const float*)d_in[14];
  const float* d2_bih = (const float*)d_in[15];
  const float* d2_bhh = (const float*)d_in[16];
  const float* w_out  = (const float*)d_in[17];
  const float* b_out  = (const float*)d_in[18];

  char* ws = (char*)d_ws;
  unsigned short* bfrag = (unsigned short*)ws;                   // 196,608 B
  const size_t OF_L2 = 4096 * 8, OF_L3 = 5632 * 8, OF_L4 = 7680 * 8, OF_PR = 11776 * 8;
  float* zbuf  = (float*)(ws + 196608);                          // 196,608 B
  float* gxbuf = (float*)(ws + 196608 + 196608);                 // 2,097,152 B

  prep_frags<<<48, 256, 0, stream>>>(e1_wih, e1_whh, e2_wih, e2_whh,
                                     d1_whh, d2_wih, d2_whh, w_out, bfrag);
  // F1: x -> (e1 -> e2, fused, role-split) -> z[B,24]
  fused_enc<<<128, 512, 0, stream>>>(
      x, bfrag, bfrag + OF_L2, e1_bih, e1_bhh, e2_bih, e2_bhh, zbuf);
  // decoder-1 constant input contribution (exact fp32)
  gx_k<<<2048, 256, 0, stream>>>(zbuf, d1_wih, d1_bih, d1_bhh, gxbuf);
  // F2: gx -> (d1 -> d2 -> proj, fused, role-split) -> recon[B,T,51] fp32
  fused_dec<<<128, 512, 0, stream>>>(
      gxbuf, bfrag + OF_L3, bfrag + OF_L4, bfrag + OF_PR,
      d2_bih, d2_bhh, b_out, (float*)d_out);
}